// Round 10
// baseline (821.073 us; speedup 1.0000x reference)
//
#include <hip/hip_runtime.h>

#define NN 100000      // nodes
#define K1 500         // input features
#define F1 128         // hidden features
#define F2 64          // output features

// ---- CSR build via two-level counting sort ----
#define NBLK   128                  // edge-chunk blocks for pa/pc
#define BSH    7                    // 128 cols per coarse bucket
#define NBUCK  ((NN + 127) >> 7)    // 782
#define NBUCKP 784
#define CAP    6144                 // max edges per bucket (mean 4096, sigma ~64)

typedef __attribute__((ext_vector_type(8))) short short8;
typedef __attribute__((ext_vector_type(4))) float floatx4;
typedef __attribute__((ext_vector_type(4))) unsigned int uintx4;

static __device__ __forceinline__ unsigned short f2bf(float f) {
    unsigned int u = __float_as_uint(f);
    unsigned int r = (u + 0x7FFF + ((u >> 16) & 1)) >> 16;   // RNE
    return (unsigned short)r;
}
static __device__ __forceinline__ void bf2x(unsigned int u, float& lo, float& hi) {
    lo = __uint_as_float(u << 16);
    hi = __uint_as_float(u & 0xffff0000u);
}
// packed fp32->bf16 (RNE), lo = first arg
static __device__ __forceinline__ unsigned int cvtpk(float lo, float hi) {
    unsigned int r;
    asm("v_cvt_pk_bf16_f32 %0, %1, %2" : "=v"(r) : "v"(lo), "v"(hi));
    return r;
}

typedef __attribute__((address_space(3))) unsigned int u32_lds;
typedef const __attribute__((address_space(1))) unsigned int u32_g;
static __device__ __forceinline__ void stage16(const float* g, float* l) {
    __builtin_amdgcn_global_load_lds((u32_g*)g, (u32_lds*)l, 16, 0, 0);
}

// ---------------- Pass A: per-block coarse histogram ----------------
__global__ __launch_bounds__(256) void k_pa(const int* __restrict__ col, int E, int chunk,
                                            int* __restrict__ HT) {
    __shared__ int hist[NBUCKP];
    for (int i = threadIdx.x; i < NBUCKP; i += 256) hist[i] = 0;
    __syncthreads();
    const int b = blockIdx.x;
    const int s = b * chunk;
    const int e0 = min(E, s + chunk);
    for (int e = s + threadIdx.x; e < e0; e += 256)
        atomicAdd(&hist[col[e] >> BSH], 1);
    __syncthreads();
    for (int i = threadIdx.x; i < NBUCK; i += 256)
        HT[i * NBLK + b] = hist[i];
}

// ---------------- bucket sums ----------------
__global__ __launch_bounds__(128) void k_bsum(const int* __restrict__ HT, int* __restrict__ S) {
    __shared__ int s[128];
    const int tid = threadIdx.x;
    s[tid] = HT[blockIdx.x * NBLK + tid];
    __syncthreads();
    for (int off = 64; off; off >>= 1) {
        if (tid < off) s[tid] += s[tid + off];
        __syncthreads();
    }
    if (tid == 0) S[blockIdx.x] = s[0];
}

// ---------------- exclusive scan of bucket sums (single block) -------------
__global__ __launch_bounds__(1024) void k_bscan(const int* __restrict__ S,
                                                int* __restrict__ BB, int nb, int E) {
    __shared__ int s[1024];
    const int tid = threadIdx.x;
    int v = (tid < nb) ? S[tid] : 0;
    s[tid] = v;
    __syncthreads();
    for (int off = 1; off < 1024; off <<= 1) {
        int t = (tid >= off) ? s[tid - off] : 0;
        __syncthreads();
        s[tid] += t;
        __syncthreads();
    }
    if (tid < nb) BB[tid] = s[tid] - v;
    if (tid == 0) BB[nb] = E;
}

// ---------------- per-(bucket,block) absolute offsets ----------------------
__global__ __launch_bounds__(128) void k_boff(int* __restrict__ HT, const int* __restrict__ BB) {
    __shared__ int s[128];
    const int tid = threadIdx.x;
    const int rowb = blockIdx.x * NBLK;
    int v = HT[rowb + tid];
    s[tid] = v;
    __syncthreads();
    for (int off = 1; off < 128; off <<= 1) {
        int t = (tid >= off) ? s[tid - off] : 0;
        __syncthreads();
        s[tid] += t;
        __syncthreads();
    }
    HT[rowb + tid] = s[tid] - v + BB[blockIdx.x];
}

// ---------------- Pass C: distribute into coarse buckets (8B pairs) --------
__global__ __launch_bounds__(256) void k_pc(const int* __restrict__ row,
                                            const int* __restrict__ col, int E, int chunk,
                                            const int* __restrict__ HT,
                                            unsigned long long* __restrict__ pairs) {
    __shared__ int cur[NBUCKP];
    const int b = blockIdx.x;
    for (int i = threadIdx.x; i < NBUCK; i += 256) cur[i] = HT[i * NBLK + b];
    __syncthreads();
    const int s = b * chunk;
    const int e0 = min(E, s + chunk);
    for (int e = s + threadIdx.x; e < e0; e += 256) {
        const int r = row[e], c = col[e];
        const int p = atomicAdd(&cur[c >> BSH], 1);
        pairs[p] = ((unsigned long long)(unsigned)c << 32) | (unsigned)r;
    }
}

// ---------------- Pass D: fine sort within bucket + ptr/dinv ----------------
__global__ __launch_bounds__(256) void k_pd(const unsigned long long* __restrict__ pairs,
                                            const int* __restrict__ BB,
                                            int* __restrict__ ptr, float* __restrict__ dinv,
                                            int* __restrict__ idx) {
    __shared__ int colcnt[128], colptr[128], cur[128];
    __shared__ int lidx[CAP];
    const int buck = blockIdx.x;
    const int base = BB[buck];
    int count = BB[buck + 1] - base;
    if (count > CAP) count = CAP;      // paranoia (uniform randint: never hit)
    const int lo = buck << BSH;
    const int tid = threadIdx.x;
    if (tid < 128) colcnt[tid] = 0;
    __syncthreads();
    for (int e = tid; e < count; e += 256) {
        const int c = (int)(pairs[base + e] >> 32);
        atomicAdd(&colcnt[c & 127], 1);
    }
    __syncthreads();
    if (tid < 128) colptr[tid] = colcnt[tid];
    __syncthreads();
    for (int off = 1; off < 128; off <<= 1) {
        int t = 0;
        if (tid < 128 && tid >= off) t = colptr[tid - off];
        __syncthreads();
        if (tid < 128) colptr[tid] += t;
        __syncthreads();
    }
    if (tid < 128) {
        const int excl = colptr[tid] - colcnt[tid];
        cur[tid] = excl;
        const int c = lo + tid;
        if (c < NN) {
            ptr[c]  = base + excl;
            dinv[c] = rsqrtf((float)colcnt[tid] + 1.0f);   // +1 self loop
        }
    }
    __syncthreads();
    for (int e = tid; e < count; e += 256) {
        const unsigned long long pr = pairs[base + e];
        const int c = (int)(pr >> 32);
        const int p = atomicAdd(&cur[c & 127], 1);
        lidx[p] = (int)(pr & 0xffffffffu);
    }
    __syncthreads();
    for (int e = tid; e < count; e += 256)
        idx[base + e] = lidx[e];
}

// ---------------- W1T: [500][128] fp32 -> [128][512] bf16 (zero pad) -------
__global__ __launch_bounds__(256) void k_w1t(const float* __restrict__ W1,
                                             unsigned short* __restrict__ W1T) {
    int t = blockIdx.x * 256 + threadIdx.x;   // 128*512 = 65536
    int n = t >> 9, k = t & 511;
    W1T[t] = (k < K1) ? f2bf(W1[k * F1 + n]) : (unsigned short)0;
}

// ---------------- GEMM1 (MFMA bf16): h'[r] = (x @ W1)[r] * dinv[r] ---------
// 32 rows/block. Whole x-tile (32x512 fp32 = 64KB) bulk-staged via
// global_load_lds in 16 issues -> ONE vmcnt drain per block. W1T slice
// preloaded to VGPRs (L2), overlapping the stage. K-loop pure LDS+MFMA.
__global__ __launch_bounds__(256, 2) void k_gemm1_mfma(
    const float* __restrict__ x,
    const unsigned short* __restrict__ W1T,   // [128][512] bf16
    const float* __restrict__ dinv,
    unsigned short* __restrict__ h)           // [NN][128] bf16, pre-scaled
{
    __shared__ __align__(16) float xs[32 * 512];   // 64 KB
    const int tid  = threadIdx.x;
    const int wave = tid >> 6;
    const int lane = tid & 63;
    const int q    = lane >> 4;          // quad: k-offset q*8
    const int m16  = lane & 15;
    const int blkRow  = blockIdx.x * 32;
    const int colBase = wave * 32;       // each wave owns 32 output cols

    // ---- W1T register preload (L2-resident), overlaps x staging ----
    short8 bw[2][16];
#pragma unroll
    for (int nt = 0; nt < 2; ++nt)
#pragma unroll
        for (int t = 0; t < 16; ++t)
            bw[nt][t] = *(const short8*)(W1T + (colBase + nt * 16 + m16) * 512 + t * 32 + q * 8);

    // ---- bulk stage: 32 rows x 128 chunks(16B), inverse-swizzled source ----
#pragma unroll
    for (int i = 0; i < 16; ++i) {
        const int s = i * 256 + tid;     // 16B slot index, 0..4095
        const int r = s >> 7;            // row 0..31
        const int c = s & 127;           // chunk 0..127
        int cs = c ^ (r & 7);            // source chunk for this slot
        if (cs > 124) cs = 124;          // row has 125 chunks; pad dup (never read)
        const float* src = x + (size_t)(blkRow + r) * K1 + cs * 4;
        stage16(src, xs + (size_t)s * 4);
    }
    __syncthreads();   // single vmcnt drain per block

    floatx4 acc[2][2];
#pragma unroll
    for (int mt = 0; mt < 2; ++mt)
#pragma unroll
        for (int nt = 0; nt < 2; ++nt) acc[mt][nt] = (floatx4){0.f, 0.f, 0.f, 0.f};

    // ---- K loop: 16 uniform steps (step 15 includes zero-padded k>=500) ----
#pragma unroll
    for (int t = 0; t < 16; ++t) {
        short8 afr[2];
#pragma unroll
        for (int mt = 0; mt < 2; ++mt) {
            const int rr = mt * 16 + m16;
            const int c0 = t * 8 + (( 2 * q )     ^ (rr & 7));
            const int c1 = t * 8 + (( 2 * q + 1 ) ^ (rr & 7));
            const floatx4 v0 = *(const floatx4*)(xs + rr * 512 + c0 * 4);
            const floatx4 v1 = *(const floatx4*)(xs + rr * 512 + c1 * 4);
            uintx4 p;
            p[0] = cvtpk(v0[0], v0[1]);
            p[1] = cvtpk(v0[2], v0[3]);
            p[2] = cvtpk(v1[0], v1[1]);
            p[3] = cvtpk(v1[2], v1[3]);
            afr[mt] = __builtin_bit_cast(short8, p);
        }
#pragma unroll
        for (int mt = 0; mt < 2; ++mt)
#pragma unroll
            for (int nt = 0; nt < 2; ++nt)
                acc[mt][nt] = __builtin_amdgcn_mfma_f32_16x16x32_bf16(
                    afr[mt], bw[nt][t], acc[mt][nt], 0, 0, 0);
    }

    // store: C/D layout col = lane&15, row = q*4 + reg; scale by dinv[row]
#pragma unroll
    for (int mt = 0; mt < 2; ++mt) {
        const int rbase = blkRow + mt * 16 + q * 4;
#pragma unroll
        for (int r = 0; r < 4; ++r) {
            const int row = rbase + r;
            const float dr = dinv[row];
#pragma unroll
            for (int nt = 0; nt < 2; ++nt)
                h[(size_t)row * F1 + colBase + nt * 16 + m16] = f2bf(acc[mt][nt][r] * dr);
        }
    }
}

// unpack one uint4 (8 bf16) into acc[B..B+7]
#define ACC8(u, B) \
    bf2x(u.x, lo, hi); acc[B+0] += lo; acc[B+1] += hi; \
    bf2x(u.y, lo, hi); acc[B+2] += lo; acc[B+3] += hi; \
    bf2x(u.z, lo, hi); acc[B+4] += lo; acc[B+5] += hi; \
    bf2x(u.w, lo, hi); acc[B+6] += lo; acc[B+7] += hi;

// ------- fused agg1+gemm2: h2'[c] = (relu(dinv[c]*(Σh'+h'[c]) + b1)@W2)*dinv[c]
// 512 threads = 8 waves/block, ONE node per wave, full occupancy (36KB LDS,
// 4 blocks/CU). 4-edge gather batches (8 uint4 issued before any unpack) for
// memory-level parallelism — round-9 profile showed VGPR=28 i.e. the compiler
// serialized to ~3 loads in flight (latency-bound, VALUBusy 50%).
// (512,8) pins VGPR <= 64 so occupancy stays 32 waves/CU.
// Accumulation order identical to round-9 -> bit-identical results.
__global__ __launch_bounds__(512, 8) void k_agg1g2(
    const int* __restrict__ ptr, const int* __restrict__ idx, int E,
    const float* __restrict__ dinv, const unsigned short* __restrict__ h,
    const float* __restrict__ b1, const float* __restrict__ W2,
    unsigned short* __restrict__ h2)
{
    __shared__ __align__(16) float W2s[F1 * F2];   // 32 KB, whole block
    __shared__ __align__(16) float xrow[8][F1];    // 4 KB: one row per wave
    const int tid  = threadIdx.x;
    const int wave = tid >> 6;
    const int lane = tid & 63;
    const int es = lane >> 3, fg = lane & 7;

    // cooperative W2 load (fp32, reused by all 8 waves)
    for (int i = tid; i < F1 * F2; i += 512) W2s[i] = W2[i];
    __syncthreads();

    const int c = blockIdx.x * 8 + wave;
    float acc[16];
#pragma unroll
    for (int j = 0; j < 16; ++j) acc[j] = 0.f;
    if (es == 0) {  // self loop
        const uint4 u0 = *(const uint4*)(h + (size_t)c * F1 + fg * 16);
        const uint4 u1 = *(const uint4*)(h + (size_t)c * F1 + fg * 16 + 8);
        float lo, hi;
        ACC8(u0, 0); ACC8(u1, 8);
    }
    const int s   = ptr[c];
    const int end = (c + 1 < NN) ? ptr[c + 1] : E;
    int e = s + es;
    // 4-edge batch: 8 gathers in flight per lane
    for (; e + 24 < end; e += 32) {
        const int r0 = idx[e], r1 = idx[e + 8], r2 = idx[e + 16], r3 = idx[e + 24];
        const uint4 a0 = *(const uint4*)(h + (size_t)r0 * F1 + fg * 16);
        const uint4 a1 = *(const uint4*)(h + (size_t)r0 * F1 + fg * 16 + 8);
        const uint4 b0 = *(const uint4*)(h + (size_t)r1 * F1 + fg * 16);
        const uint4 b1u = *(const uint4*)(h + (size_t)r1 * F1 + fg * 16 + 8);
        const uint4 c0 = *(const uint4*)(h + (size_t)r2 * F1 + fg * 16);
        const uint4 c1 = *(const uint4*)(h + (size_t)r2 * F1 + fg * 16 + 8);
        const uint4 d0 = *(const uint4*)(h + (size_t)r3 * F1 + fg * 16);
        const uint4 d1 = *(const uint4*)(h + (size_t)r3 * F1 + fg * 16 + 8);
        float lo, hi;
        ACC8(a0, 0); ACC8(a1, 8);
        ACC8(b0, 0); ACC8(b1u, 8);
        ACC8(c0, 0); ACC8(c1, 8);
        ACC8(d0, 0); ACC8(d1, 8);
    }
    // 2-edge batch
    for (; e + 8 < end; e += 16) {
        const int r0 = idx[e], r1 = idx[e + 8];
        const uint4 a0 = *(const uint4*)(h + (size_t)r0 * F1 + fg * 16);
        const uint4 a1 = *(const uint4*)(h + (size_t)r0 * F1 + fg * 16 + 8);
        const uint4 b0 = *(const uint4*)(h + (size_t)r1 * F1 + fg * 16);
        const uint4 b1u = *(const uint4*)(h + (size_t)r1 * F1 + fg * 16 + 8);
        float lo, hi;
        ACC8(a0, 0); ACC8(a1, 8);
        ACC8(b0, 0); ACC8(b1u, 8);
    }
    if (e < end) {
        const int r = idx[e];
        const uint4 u0 = *(const uint4*)(h + (size_t)r * F1 + fg * 16);
        const uint4 u1 = *(const uint4*)(h + (size_t)r * F1 + fg * 16 + 8);
        float lo, hi;
        ACC8(u0, 0); ACC8(u1, 8);
    }
#pragma unroll
    for (int j = 0; j < 16; ++j) {
        acc[j] += __shfl_xor(acc[j], 8);
        acc[j] += __shfl_xor(acc[j], 16);
        acc[j] += __shfl_xor(acc[j], 32);
    }
    const float dc = dinv[c];
    if (es == 0) {  // relu(acc*dc + b1) -> xrow[wave] (fp32 = old gemm2's xs)
        const float* bb = b1 + fg * 16;
        float* xw = &xrow[wave][fg * 16];
#pragma unroll
        for (int j = 0; j < 16; ++j)
            xw[j] = fmaxf(acc[j] * dc + bb[j], 0.f);
    }
    // same-wave DS write->read: hardware/compiler order via lgkmcnt

    // mini-GEMM: lane = output column, 32 float4 steps over k
    float h2a = 0.f;
    const float* xr = xrow[wave];
    for (int k = 0; k < F1; k += 4) {
        const float4 xv = *(const float4*)&xr[k];
        h2a += xv.x * W2s[(k + 0) * F2 + lane]
             + xv.y * W2s[(k + 1) * F2 + lane]
             + xv.z * W2s[(k + 2) * F2 + lane]
             + xv.w * W2s[(k + 3) * F2 + lane];
    }
    h2[(size_t)c * F2 + lane] = f2bf(h2a * dc);
}

// unpack one uint4 into a[0..7]
#define ACCA(u) \
    bf2x(u.x, lo, hi); a[0] += lo; a[1] += hi; \
    bf2x(u.y, lo, hi); a[2] += lo; a[3] += hi; \
    bf2x(u.z, lo, hi); a[4] += lo; a[5] += hi; \
    bf2x(u.w, lo, hi); a[6] += lo; a[7] += hi;

// ---------------- agg2: z[c] = bf16(dinv[c]*(sum h2'[r] + h2'[c]) + b2) ----
// 4-edge gather batches for MLP (same reasoning as agg1g2).
__global__ __launch_bounds__(256, 8) void k_agg2(const int* __restrict__ ptr,
                                                 const int* __restrict__ idx, int E,
                                                 const float* __restrict__ dinv,
                                                 const unsigned short* __restrict__ h2,
                                                 const float* __restrict__ b2,
                                                 unsigned short* __restrict__ z) {
    const int c    = blockIdx.x * 4 + (threadIdx.x >> 6);
    const int lane = threadIdx.x & 63;
    const int es = lane >> 3, fg = lane & 7;
    float a[8];
#pragma unroll
    for (int j = 0; j < 8; ++j) a[j] = 0.f;
    if (es == 0) {  // self loop
        const uint4 u = *(const uint4*)(h2 + (size_t)c * F2 + fg * 8);
        float lo, hi;
        ACCA(u);
    }
    const int s   = ptr[c];
    const int end = (c + 1 < NN) ? ptr[c + 1] : E;
    int e = s + es;
    for (; e + 24 < end; e += 32) {
        const int r0 = idx[e], r1 = idx[e + 8], r2 = idx[e + 16], r3 = idx[e + 24];
        const uint4 u0 = *(const uint4*)(h2 + (size_t)r0 * F2 + fg * 8);
        const uint4 u1 = *(const uint4*)(h2 + (size_t)r1 * F2 + fg * 8);
        const uint4 u2 = *(const uint4*)(h2 + (size_t)r2 * F2 + fg * 8);
        const uint4 u3 = *(const uint4*)(h2 + (size_t)r3 * F2 + fg * 8);
        float lo, hi;
        ACCA(u0); ACCA(u1); ACCA(u2); ACCA(u3);
    }
    for (; e + 8 < end; e += 16) {
        const int r0 = idx[e], r1 = idx[e + 8];
        const uint4 u0 = *(const uint4*)(h2 + (size_t)r0 * F2 + fg * 8);
        const uint4 u1 = *(const uint4*)(h2 + (size_t)r1 * F2 + fg * 8);
        float lo, hi;
        ACCA(u0); ACCA(u1);
    }
    if (e < end) {
        const int r = idx[e];
        const uint4 u = *(const uint4*)(h2 + (size_t)r * F2 + fg * 8);
        float lo, hi;
        ACCA(u);
    }
#pragma unroll
    for (int j = 0; j < 8; ++j) {
        a[j] += __shfl_xor(a[j], 8);
        a[j] += __shfl_xor(a[j], 16);
        a[j] += __shfl_xor(a[j], 32);
    }
    if (es == 0) {
        const float dc = dinv[c];
        const float4 b0 = *(const float4*)(b2 + fg * 8);
        const float4 b1v = *(const float4*)(b2 + fg * 8 + 4);
        uint4 o;
        o.x = (unsigned)f2bf(a[0] * dc + b0.x)  | ((unsigned)f2bf(a[1] * dc + b0.y)  << 16);
        o.y = (unsigned)f2bf(a[2] * dc + b0.z)  | ((unsigned)f2bf(a[3] * dc + b0.w)  << 16);
        o.z = (unsigned)f2bf(a[4] * dc + b1v.x) | ((unsigned)f2bf(a[5] * dc + b1v.y) << 16);
        o.w = (unsigned)f2bf(a[6] * dc + b1v.z) | ((unsigned)f2bf(a[7] * dc + b1v.w) << 16);
        *(uint4*)(z + (size_t)c * F2 + fg * 8) = o;
    }
}

// ---------------- decode: out[e] = dot(z[src], z[dst]) over 64 dims --------
// 8-lane slot handles FOUR consecutive edges (8 uint4 z-gathers + int4
// src/dst loads all in flight). out written as one coalesced float4/slot.
__global__ __launch_bounds__(256, 8) void k_decode(
    const int* __restrict__ src, const int* __restrict__ dst,
    int E, const unsigned short* __restrict__ z, float* __restrict__ out) {
    const long t = (long)blockIdx.x * 256 + threadIdx.x;
    const long slot = t >> 3;
    const int  l = (int)(t & 7);
    const long e0 = slot * 4;
    if (e0 >= E) return;
    const bool full = (e0 + 3 < E);
    int4 sv, dv;
    if (full) {
        sv = *(const int4*)(src + e0);
        dv = *(const int4*)(dst + e0);
    } else {
        const int eL = E - 1;
        sv.x = src[e0]; dv.x = dst[e0];
        sv.y = src[min(e0 + 1, (long)eL)]; dv.y = dst[min(e0 + 1, (long)eL)];
        sv.z = src[min(e0 + 2, (long)eL)]; dv.z = dst[min(e0 + 2, (long)eL)];
        sv.w = src[min(e0 + 3, (long)eL)]; dv.w = dst[min(e0 + 3, (long)eL)];
    }
    const uint4 us0 = *(const uint4*)(z + (size_t)sv.x * F2 + l * 8);
    const uint4 ud0 = *(const uint4*)(z + (size_t)dv.x * F2 + l * 8);
    const uint4 us1 = *(const uint4*)(z + (size_t)sv.y * F2 + l * 8);
    const uint4 ud1 = *(const uint4*)(z + (size_t)dv.y * F2 + l * 8);
    const uint4 us2 = *(const uint4*)(z + (size_t)sv.z * F2 + l * 8);
    const uint4 ud2 = *(const uint4*)(z + (size_t)dv.z * F2 + l * 8);
    const uint4 us3 = *(const uint4*)(z + (size_t)sv.w * F2 + l * 8);
    const uint4 ud3 = *(const uint4*)(z + (size_t)dv.w * F2 + l * 8);
    float sl, sh, dl, dh;
#define DOTE(us, ud, v) \
    bf2x(us.x, sl, sh); bf2x(ud.x, dl, dh); v  = sl * dl + sh * dh; \
    bf2x(us.y, sl, sh); bf2x(ud.y, dl, dh); v += sl * dl + sh * dh; \
    bf2x(us.z, sl, sh); bf2x(ud.z, dl, dh); v += sl * dl + sh * dh; \
    bf2x(us.w, sl, sh); bf2x(ud.w, dl, dh); v += sl * dl + sh * dh;
    float v0, v1, v2, v3;
    DOTE(us0, ud0, v0);
    DOTE(us1, ud1, v1);
    DOTE(us2, ud2, v2);
    DOTE(us3, ud3, v3);
#undef DOTE
    v0 += __shfl_down(v0, 4, 8); v1 += __shfl_down(v1, 4, 8);
    v2 += __shfl_down(v2, 4, 8); v3 += __shfl_down(v3, 4, 8);
    v0 += __shfl_down(v0, 2, 8); v1 += __shfl_down(v1, 2, 8);
    v2 += __shfl_down(v2, 2, 8); v3 += __shfl_down(v3, 2, 8);
    v0 += __shfl_down(v0, 1, 8); v1 += __shfl_down(v1, 1, 8);
    v2 += __shfl_down(v2, 1, 8); v3 += __shfl_down(v3, 1, 8);
    if (l == 0) {
        if (full) {
            float4 o = {v0, v1, v2, v3};
            *(float4*)(out + e0) = o;
        } else {
            out[e0] = v0;
            if (e0 + 1 < E) out[e0 + 1] = v1;
            if (e0 + 2 < E) out[e0 + 2] = v2;
            if (e0 + 3 < E) out[e0 + 3] = v3;
        }
    }
}

extern "C" void kernel_launch(void* const* d_in, const int* in_sizes, int n_in,
                              void* d_out, int out_size, void* d_ws, size_t ws_size,
                              hipStream_t stream) {
    const float* x  = (const float*)d_in[0];
    const float* W1 = (const float*)d_in[1];
    const float* b1 = (const float*)d_in[2];
    const float* W2 = (const float*)d_in[3];
    const float* b2 = (const float*)d_in[4];
    const int*   ei = (const int*)d_in[5];
    const int E = in_sizes[5] / 2;
    const int* rowp = ei;        // edge_index[0] = source (gather side)
    const int* colp = ei + E;    // edge_index[1] = destination (scatter side)

    // ---- workspace layout (all sub-offsets multiple of 16 bytes) ----
    char* wsb = (char*)d_ws;
    float* dinv = (float*)wsb;                 wsb += 100352 * 4;
    int*   ptr  = (int*)wsb;                   wsb += 100352 * 4;
    int*   S    = (int*)wsb;                   wsb += 1024 * 4;
    int*   BB   = (int*)wsb;                   wsb += 1024 * 4;
    int*   HT   = (int*)wsb;                   wsb += (size_t)1024 * NBLK * 4;
    int*   idx  = (int*)wsb;                   wsb += (size_t)E * 4;
    unsigned short* W1T = (unsigned short*)wsb; wsb += 128 * 512 * 2;
    unsigned short* hbf = (unsigned short*)wsb; wsb += (size_t)NN * F1 * 2;  // h' bf16; reused as z (bf16)
    unsigned short* h2 = (unsigned short*)wsb; wsb += (size_t)NN * F2 * 2;   // h2' bf16
    unsigned long long* pairs = (unsigned long long*)wsb; wsb += (size_t)E * 8;
    unsigned short* z = hbf;                   // dead before z written
    float* out  = (float*)d_out;

    const int chunk = (E + NBLK - 1) / NBLK;

    // ---- CSR build (counting sort, no global atomics, no memsets) ----
    k_pa   <<<NBLK, 256, 0, stream>>>(colp, E, chunk, HT);
    k_bsum <<<NBUCK, 128, 0, stream>>>(HT, S);
    k_bscan<<<1, 1024, 0, stream>>>(S, BB, NBUCK, E);
    k_boff <<<NBUCK, 128, 0, stream>>>(HT, BB);
    k_pc   <<<NBLK, 256, 0, stream>>>(rowp, colp, E, chunk, HT, pairs);
    k_pd   <<<NBUCK, 256, 0, stream>>>(pairs, BB, ptr, dinv, idx);

    // ---- layer 1 ----
    k_w1t<<<256, 256, 0, stream>>>(W1, W1T);
    k_gemm1_mfma<<<NN / 32, 256, 0, stream>>>(x, W1T, dinv, hbf);

    // ---- layer 1 aggregate + layer 2 GEMM (fused, 8 waves/block) ----
    k_agg1g2<<<NN / 8, 512, 0, stream>>>(ptr, idx, E, dinv, hbf, b1, W2, h2);

    // ---- layer 2 aggregate ----
    k_agg2<<<NN / 4, 256, 0, stream>>>(ptr, idx, E, dinv, h2, b2, z);

    // ---- decode (4 edges per 8-lane slot) ----
    const long slots = ((long)E + 3) / 4;
    const long dthreads = slots * 8;
    k_decode<<<(int)((dthreads + 255) / 256), 256, 0, stream>>>(
        rowp, colp, E, z, out);
}

// Round 11
// 755.047 us; speedup vs baseline: 1.0874x; 1.0874x over previous
//
#include <hip/hip_runtime.h>

#define NN 100000      // nodes
#define K1 500         // input features
#define F1 128         // hidden features
#define F2 64          // output features

// ---- CSR build via two-level counting sort ----
#define NBLK   128                  // edge-chunk blocks for pa/pc
#define BSH    7                    // 128 cols per coarse bucket
#define NBUCK  ((NN + 127) >> 7)    // 782
#define NBUCKP 784
#define CAP    6144                 // max edges per bucket (mean 4096, sigma ~64)

typedef __attribute__((ext_vector_type(8))) short short8;
typedef __attribute__((ext_vector_type(4))) float floatx4;
typedef __attribute__((ext_vector_type(4))) unsigned int uintx4;

static __device__ __forceinline__ unsigned short f2bf(float f) {
    unsigned int u = __float_as_uint(f);
    unsigned int r = (u + 0x7FFF + ((u >> 16) & 1)) >> 16;   // RNE
    return (unsigned short)r;
}
static __device__ __forceinline__ void bf2x(unsigned int u, float& lo, float& hi) {
    lo = __uint_as_float(u << 16);
    hi = __uint_as_float(u & 0xffff0000u);
}
// packed fp32->bf16 (RNE), lo = first arg
static __device__ __forceinline__ unsigned int cvtpk(float lo, float hi) {
    unsigned int r;
    asm("v_cvt_pk_bf16_f32 %0, %1, %2" : "=v"(r) : "v"(lo), "v"(hi));
    return r;
}

typedef __attribute__((address_space(3))) unsigned int u32_lds;
typedef const __attribute__((address_space(1))) unsigned int u32_g;
static __device__ __forceinline__ void stage16(const float* g, float* l) {
    __builtin_amdgcn_global_load_lds((u32_g*)g, (u32_lds*)l, 16, 0, 0);
}

// ---------------- Pass A: per-block coarse histogram ----------------
__global__ __launch_bounds__(256) void k_pa(const int* __restrict__ col, int E, int chunk,
                                            int* __restrict__ HT) {
    __shared__ int hist[NBUCKP];
    for (int i = threadIdx.x; i < NBUCKP; i += 256) hist[i] = 0;
    __syncthreads();
    const int b = blockIdx.x;
    const int s = b * chunk;
    const int e0 = min(E, s + chunk);
    for (int e = s + threadIdx.x; e < e0; e += 256)
        atomicAdd(&hist[col[e] >> BSH], 1);
    __syncthreads();
    for (int i = threadIdx.x; i < NBUCK; i += 256)
        HT[i * NBLK + b] = hist[i];
}

// ---------------- bucket sums ----------------
__global__ __launch_bounds__(128) void k_bsum(const int* __restrict__ HT, int* __restrict__ S) {
    __shared__ int s[128];
    const int tid = threadIdx.x;
    s[tid] = HT[blockIdx.x * NBLK + tid];
    __syncthreads();
    for (int off = 64; off; off >>= 1) {
        if (tid < off) s[tid] += s[tid + off];
        __syncthreads();
    }
    if (tid == 0) S[blockIdx.x] = s[0];
}

// ---------------- exclusive scan of bucket sums (single block) -------------
__global__ __launch_bounds__(1024) void k_bscan(const int* __restrict__ S,
                                                int* __restrict__ BB, int nb, int E) {
    __shared__ int s[1024];
    const int tid = threadIdx.x;
    int v = (tid < nb) ? S[tid] : 0;
    s[tid] = v;
    __syncthreads();
    for (int off = 1; off < 1024; off <<= 1) {
        int t = (tid >= off) ? s[tid - off] : 0;
        __syncthreads();
        s[tid] += t;
        __syncthreads();
    }
    if (tid < nb) BB[tid] = s[tid] - v;
    if (tid == 0) BB[nb] = E;
}

// ---------------- per-(bucket,block) absolute offsets ----------------------
__global__ __launch_bounds__(128) void k_boff(int* __restrict__ HT, const int* __restrict__ BB) {
    __shared__ int s[128];
    const int tid = threadIdx.x;
    const int rowb = blockIdx.x * NBLK;
    int v = HT[rowb + tid];
    s[tid] = v;
    __syncthreads();
    for (int off = 1; off < 128; off <<= 1) {
        int t = (tid >= off) ? s[tid - off] : 0;
        __syncthreads();
        s[tid] += t;
        __syncthreads();
    }
    HT[rowb + tid] = s[tid] - v + BB[blockIdx.x];
}

// ---------------- Pass C: distribute into coarse buckets (8B pairs) --------
__global__ __launch_bounds__(256) void k_pc(const int* __restrict__ row,
                                            const int* __restrict__ col, int E, int chunk,
                                            const int* __restrict__ HT,
                                            unsigned long long* __restrict__ pairs) {
    __shared__ int cur[NBUCKP];
    const int b = blockIdx.x;
    for (int i = threadIdx.x; i < NBUCK; i += 256) cur[i] = HT[i * NBLK + b];
    __syncthreads();
    const int s = b * chunk;
    const int e0 = min(E, s + chunk);
    for (int e = s + threadIdx.x; e < e0; e += 256) {
        const int r = row[e], c = col[e];
        const int p = atomicAdd(&cur[c >> BSH], 1);
        pairs[p] = ((unsigned long long)(unsigned)c << 32) | (unsigned)r;
    }
}

// ---------------- Pass D: fine sort within bucket + ptr/dinv ----------------
__global__ __launch_bounds__(256) void k_pd(const unsigned long long* __restrict__ pairs,
                                            const int* __restrict__ BB,
                                            int* __restrict__ ptr, float* __restrict__ dinv,
                                            int* __restrict__ idx) {
    __shared__ int colcnt[128], colptr[128], cur[128];
    __shared__ int lidx[CAP];
    const int buck = blockIdx.x;
    const int base = BB[buck];
    int count = BB[buck + 1] - base;
    if (count > CAP) count = CAP;      // paranoia (uniform randint: never hit)
    const int lo = buck << BSH;
    const int tid = threadIdx.x;
    if (tid < 128) colcnt[tid] = 0;
    __syncthreads();
    for (int e = tid; e < count; e += 256) {
        const int c = (int)(pairs[base + e] >> 32);
        atomicAdd(&colcnt[c & 127], 1);
    }
    __syncthreads();
    if (tid < 128) colptr[tid] = colcnt[tid];
    __syncthreads();
    for (int off = 1; off < 128; off <<= 1) {
        int t = 0;
        if (tid < 128 && tid >= off) t = colptr[tid - off];
        __syncthreads();
        if (tid < 128) colptr[tid] += t;
        __syncthreads();
    }
    if (tid < 128) {
        const int excl = colptr[tid] - colcnt[tid];
        cur[tid] = excl;
        const int c = lo + tid;
        if (c < NN) {
            ptr[c]  = base + excl;
            dinv[c] = rsqrtf((float)colcnt[tid] + 1.0f);   // +1 self loop
        }
    }
    __syncthreads();
    for (int e = tid; e < count; e += 256) {
        const unsigned long long pr = pairs[base + e];
        const int c = (int)(pr >> 32);
        const int p = atomicAdd(&cur[c & 127], 1);
        lidx[p] = (int)(pr & 0xffffffffu);
    }
    __syncthreads();
    for (int e = tid; e < count; e += 256)
        idx[base + e] = lidx[e];
}

// ---------------- W1T: [500][128] fp32 -> [128][512] bf16 (zero pad) -------
__global__ __launch_bounds__(256) void k_w1t(const float* __restrict__ W1,
                                             unsigned short* __restrict__ W1T) {
    int t = blockIdx.x * 256 + threadIdx.x;   // 128*512 = 65536
    int n = t >> 9, k = t & 511;
    W1T[t] = (k < K1) ? f2bf(W1[k * F1 + n]) : (unsigned short)0;
}

// ---------------- GEMM1 (MFMA bf16): h'[r] = (x @ W1)[r] * dinv[r] ---------
// 32 rows/block. Whole x-tile (32x512 fp32 = 64KB) bulk-staged via
// global_load_lds in 16 issues -> ONE vmcnt drain per block. W1T slice
// preloaded to VGPRs (L2), overlapping the stage. K-loop pure LDS+MFMA.
__global__ __launch_bounds__(256, 2) void k_gemm1_mfma(
    const float* __restrict__ x,
    const unsigned short* __restrict__ W1T,   // [128][512] bf16
    const float* __restrict__ dinv,
    unsigned short* __restrict__ h)           // [NN][128] bf16, pre-scaled
{
    __shared__ __align__(16) float xs[32 * 512];   // 64 KB
    const int tid  = threadIdx.x;
    const int wave = tid >> 6;
    const int lane = tid & 63;
    const int q    = lane >> 4;          // quad: k-offset q*8
    const int m16  = lane & 15;
    const int blkRow  = blockIdx.x * 32;
    const int colBase = wave * 32;       // each wave owns 32 output cols

    // ---- W1T register preload (L2-resident), overlaps x staging ----
    short8 bw[2][16];
#pragma unroll
    for (int nt = 0; nt < 2; ++nt)
#pragma unroll
        for (int t = 0; t < 16; ++t)
            bw[nt][t] = *(const short8*)(W1T + (colBase + nt * 16 + m16) * 512 + t * 32 + q * 8);

    // ---- bulk stage: 32 rows x 128 chunks(16B), inverse-swizzled source ----
#pragma unroll
    for (int i = 0; i < 16; ++i) {
        const int s = i * 256 + tid;     // 16B slot index, 0..4095
        const int r = s >> 7;            // row 0..31
        const int c = s & 127;           // chunk 0..127
        int cs = c ^ (r & 7);            // source chunk for this slot
        if (cs > 124) cs = 124;          // row has 125 chunks; pad dup (never read)
        const float* src = x + (size_t)(blkRow + r) * K1 + cs * 4;
        stage16(src, xs + (size_t)s * 4);
    }
    __syncthreads();   // single vmcnt drain per block

    floatx4 acc[2][2];
#pragma unroll
    for (int mt = 0; mt < 2; ++mt)
#pragma unroll
        for (int nt = 0; nt < 2; ++nt) acc[mt][nt] = (floatx4){0.f, 0.f, 0.f, 0.f};

    // ---- K loop: 16 uniform steps (step 15 includes zero-padded k>=500) ----
#pragma unroll
    for (int t = 0; t < 16; ++t) {
        short8 afr[2];
#pragma unroll
        for (int mt = 0; mt < 2; ++mt) {
            const int rr = mt * 16 + m16;
            const int c0 = t * 8 + (( 2 * q )     ^ (rr & 7));
            const int c1 = t * 8 + (( 2 * q + 1 ) ^ (rr & 7));
            const floatx4 v0 = *(const floatx4*)(xs + rr * 512 + c0 * 4);
            const floatx4 v1 = *(const floatx4*)(xs + rr * 512 + c1 * 4);
            uintx4 p;
            p[0] = cvtpk(v0[0], v0[1]);
            p[1] = cvtpk(v0[2], v0[3]);
            p[2] = cvtpk(v1[0], v1[1]);
            p[3] = cvtpk(v1[2], v1[3]);
            afr[mt] = __builtin_bit_cast(short8, p);
        }
#pragma unroll
        for (int mt = 0; mt < 2; ++mt)
#pragma unroll
            for (int nt = 0; nt < 2; ++nt)
                acc[mt][nt] = __builtin_amdgcn_mfma_f32_16x16x32_bf16(
                    afr[mt], bw[nt][t], acc[mt][nt], 0, 0, 0);
    }

    // store: C/D layout col = lane&15, row = q*4 + reg; scale by dinv[row]
#pragma unroll
    for (int mt = 0; mt < 2; ++mt) {
        const int rbase = blkRow + mt * 16 + q * 4;
#pragma unroll
        for (int r = 0; r < 4; ++r) {
            const int row = rbase + r;
            const float dr = dinv[row];
#pragma unroll
            for (int nt = 0; nt < 2; ++nt)
                h[(size_t)row * F1 + colBase + nt * 16 + m16] = f2bf(acc[mt][nt][r] * dr);
        }
    }
}

// ------- fused agg1+gemm2: h2'[c] = (relu(dinv[c]*(Σh'+h'[c]) + b1)@W2)*dinv[c]
// 512 threads = 8 waves/block, ONE node per wave. W2s (32KB fp32) shared by
// 8 waves -> LDS 36KB, 4 blocks/CU x 512 thr = 32 waves/CU = FULL occupancy.
// 2-edge batch (round-9 form, 28 VGPR, no spills — the round-10 4-edge batch
// made the compiler spill to scratch: WRITE_SIZE 12.5->352MB, dur +62us).
// Arithmetic identical to the former agg1->gemm2 pair (fp32 throughout).
__global__ __launch_bounds__(512) void k_agg1g2(
    const int* __restrict__ ptr, const int* __restrict__ idx, int E,
    const float* __restrict__ dinv, const unsigned short* __restrict__ h,
    const float* __restrict__ b1, const float* __restrict__ W2,
    unsigned short* __restrict__ h2)
{
    __shared__ __align__(16) float W2s[F1 * F2];   // 32 KB, whole block
    __shared__ __align__(16) float xrow[8][F1];    // 4 KB: one row per wave
    const int tid  = threadIdx.x;
    const int wave = tid >> 6;
    const int lane = tid & 63;
    const int es = lane >> 3, fg = lane & 7;

    // cooperative W2 load (fp32, reused by all 8 waves)
    for (int i = tid; i < F1 * F2; i += 512) W2s[i] = W2[i];
    __syncthreads();

    const int c = blockIdx.x * 8 + wave;
    float acc[16];
#pragma unroll
    for (int j = 0; j < 16; ++j) acc[j] = 0.f;
    if (es == 0) {  // self loop
        const uint4 u0 = *(const uint4*)(h + (size_t)c * F1 + fg * 16);
        const uint4 u1 = *(const uint4*)(h + (size_t)c * F1 + fg * 16 + 8);
        bf2x(u0.x, acc[0], acc[1]);  bf2x(u0.y, acc[2], acc[3]);
        bf2x(u0.z, acc[4], acc[5]);  bf2x(u0.w, acc[6], acc[7]);
        bf2x(u1.x, acc[8], acc[9]);  bf2x(u1.y, acc[10], acc[11]);
        bf2x(u1.z, acc[12], acc[13]); bf2x(u1.w, acc[14], acc[15]);
    }
    const int s   = ptr[c];
    const int end = (c + 1 < NN) ? ptr[c + 1] : E;
    int e = s + es;
    for (; e + 8 < end; e += 16) {
        const int r0 = idx[e], r1 = idx[e + 8];
        const uint4 u00 = *(const uint4*)(h + (size_t)r0 * F1 + fg * 16);
        const uint4 u01 = *(const uint4*)(h + (size_t)r0 * F1 + fg * 16 + 8);
        const uint4 u10 = *(const uint4*)(h + (size_t)r1 * F1 + fg * 16);
        const uint4 u11 = *(const uint4*)(h + (size_t)r1 * F1 + fg * 16 + 8);
        float lo, hi;
        bf2x(u00.x, lo, hi); acc[0] += lo; acc[1] += hi;
        bf2x(u00.y, lo, hi); acc[2] += lo; acc[3] += hi;
        bf2x(u00.z, lo, hi); acc[4] += lo; acc[5] += hi;
        bf2x(u00.w, lo, hi); acc[6] += lo; acc[7] += hi;
        bf2x(u01.x, lo, hi); acc[8] += lo; acc[9] += hi;
        bf2x(u01.y, lo, hi); acc[10] += lo; acc[11] += hi;
        bf2x(u01.z, lo, hi); acc[12] += lo; acc[13] += hi;
        bf2x(u01.w, lo, hi); acc[14] += lo; acc[15] += hi;
        bf2x(u10.x, lo, hi); acc[0] += lo; acc[1] += hi;
        bf2x(u10.y, lo, hi); acc[2] += lo; acc[3] += hi;
        bf2x(u10.z, lo, hi); acc[4] += lo; acc[5] += hi;
        bf2x(u10.w, lo, hi); acc[6] += lo; acc[7] += hi;
        bf2x(u11.x, lo, hi); acc[8] += lo; acc[9] += hi;
        bf2x(u11.y, lo, hi); acc[10] += lo; acc[11] += hi;
        bf2x(u11.z, lo, hi); acc[12] += lo; acc[13] += hi;
        bf2x(u11.w, lo, hi); acc[14] += lo; acc[15] += hi;
    }
    if (e < end) {
        const int r = idx[e];
        const uint4 u0 = *(const uint4*)(h + (size_t)r * F1 + fg * 16);
        const uint4 u1 = *(const uint4*)(h + (size_t)r * F1 + fg * 16 + 8);
        float lo, hi;
        bf2x(u0.x, lo, hi); acc[0] += lo; acc[1] += hi;
        bf2x(u0.y, lo, hi); acc[2] += lo; acc[3] += hi;
        bf2x(u0.z, lo, hi); acc[4] += lo; acc[5] += hi;
        bf2x(u0.w, lo, hi); acc[6] += lo; acc[7] += hi;
        bf2x(u1.x, lo, hi); acc[8] += lo; acc[9] += hi;
        bf2x(u1.y, lo, hi); acc[10] += lo; acc[11] += hi;
        bf2x(u1.z, lo, hi); acc[12] += lo; acc[13] += hi;
        bf2x(u1.w, lo, hi); acc[14] += lo; acc[15] += hi;
    }
#pragma unroll
    for (int j = 0; j < 16; ++j) {
        acc[j] += __shfl_xor(acc[j], 8);
        acc[j] += __shfl_xor(acc[j], 16);
        acc[j] += __shfl_xor(acc[j], 32);
    }
    const float dc = dinv[c];
    if (es == 0) {  // relu(acc*dc + b1) -> xrow[wave] (fp32 = old gemm2's xs)
        const float* bb = b1 + fg * 16;
        float* xw = &xrow[wave][fg * 16];
#pragma unroll
        for (int j = 0; j < 16; ++j)
            xw[j] = fmaxf(acc[j] * dc + bb[j], 0.f);
    }
    // same-wave DS write->read: hardware/compiler order via lgkmcnt

    // mini-GEMM: lane = output column, 32 float4 steps over k
    float h2a = 0.f;
    const float* xr = xrow[wave];
    for (int k = 0; k < F1; k += 4) {
        const float4 xv = *(const float4*)&xr[k];
        h2a += xv.x * W2s[(k + 0) * F2 + lane]
             + xv.y * W2s[(k + 1) * F2 + lane]
             + xv.z * W2s[(k + 2) * F2 + lane]
             + xv.w * W2s[(k + 3) * F2 + lane];
    }
    h2[(size_t)c * F2 + lane] = f2bf(h2a * dc);
}

// unpack one uint4 into a[0..7]
#define ACCA(u) \
    bf2x(u.x, lo, hi); a[0] += lo; a[1] += hi; \
    bf2x(u.y, lo, hi); a[2] += lo; a[3] += hi; \
    bf2x(u.z, lo, hi); a[4] += lo; a[5] += hi; \
    bf2x(u.w, lo, hi); a[6] += lo; a[7] += hi;

// ---------------- agg2: z[c] = bf16(dinv[c]*(sum h2'[r] + h2'[c]) + b2) ----
// 4-edge gather batches (4 uint4 in flight; no spills at 8 acc).
__global__ __launch_bounds__(256, 8) void k_agg2(const int* __restrict__ ptr,
                                                 const int* __restrict__ idx, int E,
                                                 const float* __restrict__ dinv,
                                                 const unsigned short* __restrict__ h2,
                                                 const float* __restrict__ b2,
                                                 unsigned short* __restrict__ z) {
    const int c    = blockIdx.x * 4 + (threadIdx.x >> 6);
    const int lane = threadIdx.x & 63;
    const int es = lane >> 3, fg = lane & 7;
    float a[8];
#pragma unroll
    for (int j = 0; j < 8; ++j) a[j] = 0.f;
    if (es == 0) {  // self loop
        const uint4 u = *(const uint4*)(h2 + (size_t)c * F2 + fg * 8);
        float lo, hi;
        ACCA(u);
    }
    const int s   = ptr[c];
    const int end = (c + 1 < NN) ? ptr[c + 1] : E;
    int e = s + es;
    for (; e + 24 < end; e += 32) {
        const int r0 = idx[e], r1 = idx[e + 8], r2 = idx[e + 16], r3 = idx[e + 24];
        const uint4 u0 = *(const uint4*)(h2 + (size_t)r0 * F2 + fg * 8);
        const uint4 u1 = *(const uint4*)(h2 + (size_t)r1 * F2 + fg * 8);
        const uint4 u2 = *(const uint4*)(h2 + (size_t)r2 * F2 + fg * 8);
        const uint4 u3 = *(const uint4*)(h2 + (size_t)r3 * F2 + fg * 8);
        float lo, hi;
        ACCA(u0); ACCA(u1); ACCA(u2); ACCA(u3);
    }
    for (; e + 8 < end; e += 16) {
        const int r0 = idx[e], r1 = idx[e + 8];
        const uint4 u0 = *(const uint4*)(h2 + (size_t)r0 * F2 + fg * 8);
        const uint4 u1 = *(const uint4*)(h2 + (size_t)r1 * F2 + fg * 8);
        float lo, hi;
        ACCA(u0); ACCA(u1);
    }
    if (e < end) {
        const int r = idx[e];
        const uint4 u = *(const uint4*)(h2 + (size_t)r * F2 + fg * 8);
        float lo, hi;
        ACCA(u);
    }
#pragma unroll
    for (int j = 0; j < 8; ++j) {
        a[j] += __shfl_xor(a[j], 8);
        a[j] += __shfl_xor(a[j], 16);
        a[j] += __shfl_xor(a[j], 32);
    }
    if (es == 0) {
        const float dc = dinv[c];
        const float4 b0 = *(const float4*)(b2 + fg * 8);
        const float4 b1v = *(const float4*)(b2 + fg * 8 + 4);
        uint4 o;
        o.x = (unsigned)f2bf(a[0] * dc + b0.x)  | ((unsigned)f2bf(a[1] * dc + b0.y)  << 16);
        o.y = (unsigned)f2bf(a[2] * dc + b0.z)  | ((unsigned)f2bf(a[3] * dc + b0.w)  << 16);
        o.z = (unsigned)f2bf(a[4] * dc + b1v.x) | ((unsigned)f2bf(a[5] * dc + b1v.y) << 16);
        o.w = (unsigned)f2bf(a[6] * dc + b1v.z) | ((unsigned)f2bf(a[7] * dc + b1v.w) << 16);
        *(uint4*)(z + (size_t)c * F2 + fg * 8) = o;
    }
}

// ---------------- decode: out[e] = dot(z[src], z[dst]) over 64 dims --------
// 8-lane slot handles FOUR consecutive edges (8 uint4 z-gathers + int4
// src/dst loads all in flight). out written as one coalesced float4/slot.
__global__ __launch_bounds__(256, 8) void k_decode(
    const int* __restrict__ src, const int* __restrict__ dst,
    int E, const unsigned short* __restrict__ z, float* __restrict__ out) {
    const long t = (long)blockIdx.x * 256 + threadIdx.x;
    const long slot = t >> 3;
    const int  l = (int)(t & 7);
    const long e0 = slot * 4;
    if (e0 >= E) return;
    const bool full = (e0 + 3 < E);
    int4 sv, dv;
    if (full) {
        sv = *(const int4*)(src + e0);
        dv = *(const int4*)(dst + e0);
    } else {
        const int eL = E - 1;
        sv.x = src[e0]; dv.x = dst[e0];
        sv.y = src[min(e0 + 1, (long)eL)]; dv.y = dst[min(e0 + 1, (long)eL)];
        sv.z = src[min(e0 + 2, (long)eL)]; dv.z = dst[min(e0 + 2, (long)eL)];
        sv.w = src[min(e0 + 3, (long)eL)]; dv.w = dst[min(e0 + 3, (long)eL)];
    }
    const uint4 us0 = *(const uint4*)(z + (size_t)sv.x * F2 + l * 8);
    const uint4 ud0 = *(const uint4*)(z + (size_t)dv.x * F2 + l * 8);
    const uint4 us1 = *(const uint4*)(z + (size_t)sv.y * F2 + l * 8);
    const uint4 ud1 = *(const uint4*)(z + (size_t)dv.y * F2 + l * 8);
    const uint4 us2 = *(const uint4*)(z + (size_t)sv.z * F2 + l * 8);
    const uint4 ud2 = *(const uint4*)(z + (size_t)dv.z * F2 + l * 8);
    const uint4 us3 = *(const uint4*)(z + (size_t)sv.w * F2 + l * 8);
    const uint4 ud3 = *(const uint4*)(z + (size_t)dv.w * F2 + l * 8);
    float sl, sh, dl, dh;
#define DOTE(us, ud, v) \
    bf2x(us.x, sl, sh); bf2x(ud.x, dl, dh); v  = sl * dl + sh * dh; \
    bf2x(us.y, sl, sh); bf2x(ud.y, dl, dh); v += sl * dl + sh * dh; \
    bf2x(us.z, sl, sh); bf2x(ud.z, dl, dh); v += sl * dl + sh * dh; \
    bf2x(us.w, sl, sh); bf2x(ud.w, dl, dh); v += sl * dl + sh * dh;
    float v0, v1, v2, v3;
    DOTE(us0, ud0, v0);
    DOTE(us1, ud1, v1);
    DOTE(us2, ud2, v2);
    DOTE(us3, ud3, v3);
#undef DOTE
    v0 += __shfl_down(v0, 4, 8); v1 += __shfl_down(v1, 4, 8);
    v2 += __shfl_down(v2, 4, 8); v3 += __shfl_down(v3, 4, 8);
    v0 += __shfl_down(v0, 2, 8); v1 += __shfl_down(v1, 2, 8);
    v2 += __shfl_down(v2, 2, 8); v3 += __shfl_down(v3, 2, 8);
    v0 += __shfl_down(v0, 1, 8); v1 += __shfl_down(v1, 1, 8);
    v2 += __shfl_down(v2, 1, 8); v3 += __shfl_down(v3, 1, 8);
    if (l == 0) {
        if (full) {
            float4 o = {v0, v1, v2, v3};
            *(float4*)(out + e0) = o;
        } else {
            out[e0] = v0;
            if (e0 + 1 < E) out[e0 + 1] = v1;
            if (e0 + 2 < E) out[e0 + 2] = v2;
            if (e0 + 3 < E) out[e0 + 3] = v3;
        }
    }
}

extern "C" void kernel_launch(void* const* d_in, const int* in_sizes, int n_in,
                              void* d_out, int out_size, void* d_ws, size_t ws_size,
                              hipStream_t stream) {
    const float* x  = (const float*)d_in[0];
    const float* W1 = (const float*)d_in[1];
    const float* b1 = (const float*)d_in[2];
    const float* W2 = (const float*)d_in[3];
    const float* b2 = (const float*)d_in[4];
    const int*   ei = (const int*)d_in[5];
    const int E = in_sizes[5] / 2;
    const int* rowp = ei;        // edge_index[0] = source (gather side)
    const int* colp = ei + E;    // edge_index[1] = destination (scatter side)

    // ---- workspace layout (all sub-offsets multiple of 16 bytes) ----
    char* wsb = (char*)d_ws;
    float* dinv = (float*)wsb;                 wsb += 100352 * 4;
    int*   ptr  = (int*)wsb;                   wsb += 100352 * 4;
    int*   S    = (int*)wsb;                   wsb += 1024 * 4;
    int*   BB   = (int*)wsb;                   wsb += 1024 * 4;
    int*   HT   = (int*)wsb;                   wsb += (size_t)1024 * NBLK * 4;
    int*   idx  = (int*)wsb;                   wsb += (size_t)E * 4;
    unsigned short* W1T = (unsigned short*)wsb; wsb += 128 * 512 * 2;
    unsigned short* hbf = (unsigned short*)wsb; wsb += (size_t)NN * F1 * 2;  // h' bf16; reused as z (bf16)
    unsigned short* h2 = (unsigned short*)wsb; wsb += (size_t)NN * F2 * 2;   // h2' bf16
    unsigned long long* pairs = (unsigned long long*)wsb; wsb += (size_t)E * 8;
    unsigned short* z = hbf;                   // dead before z written
    float* out  = (float*)d_out;

    const int chunk = (E + NBLK - 1) / NBLK;

    // ---- CSR build (counting sort, no global atomics, no memsets) ----
    k_pa   <<<NBLK, 256, 0, stream>>>(colp, E, chunk, HT);
    k_bsum <<<NBUCK, 128, 0, stream>>>(HT, S);
    k_bscan<<<1, 1024, 0, stream>>>(S, BB, NBUCK, E);
    k_boff <<<NBUCK, 128, 0, stream>>>(HT, BB);
    k_pc   <<<NBLK, 256, 0, stream>>>(rowp, colp, E, chunk, HT, pairs);
    k_pd   <<<NBUCK, 256, 0, stream>>>(pairs, BB, ptr, dinv, idx);

    // ---- layer 1 ----
    k_w1t<<<256, 256, 0, stream>>>(W1, W1T);
    k_gemm1_mfma<<<NN / 32, 256, 0, stream>>>(x, W1T, dinv, hbf);

    // ---- layer 1 aggregate + layer 2 GEMM (fused, 8 waves/block) ----
    k_agg1g2<<<NN / 8, 512, 0, stream>>>(ptr, idx, E, dinv, hbf, b1, W2, h2);

    // ---- layer 2 aggregate ----
    k_agg2<<<NN / 4, 256, 0, stream>>>(ptr, idx, E, dinv, h2, b2, z);

    // ---- decode (4 edges per 8-lane slot) ----
    const long slots = ((long)E + 3) / 4;
    const long dthreads = slots * 8;
    k_decode<<<(int)((dthreads + 255) / 256), 256, 0, stream>>>(
        rowp, colp, E, z, out);
}